// Round 7
// baseline (68.298 us; speedup 1.0000x reference)
//
#include <hip/hip_runtime.h>

#define NROWS 8192
#define NCLS  100
#define LN2   0.6931471805599453f
#define LOG2E 1.4426950408889634f

#if __has_builtin(__builtin_amdgcn_exp2f)
#define EXP2F(x) __builtin_amdgcn_exp2f(x)
#else
#define EXP2F(x) __expf((x) * LN2)
#endif
#if __has_builtin(__builtin_amdgcn_logf)
#define LOG2F(x) __builtin_amdgcn_logf(x)
#else
#define LOG2F(x) (__logf(x) * LOG2E)
#endif

// accumulate one symmetric pair-term: f(|d|) = |d| + 2*log2(1+2^-|d|)
// via A += |d|;  P *= (1 + 2^-|d|)
#define ACC(D0, A, P) { float d_ = (D0); A += fabsf(d_); \
                        P = fmaf(P, EXP2F(-fabsf(d_)), P); }

#define TILE16(aq, bq, A, P) \
    ACC(aq.x - bq.x, A, P) ACC(aq.x - bq.y, A, P) ACC(aq.x - bq.z, A, P) ACC(aq.x - bq.w, A, P) \
    ACC(aq.y - bq.x, A, P) ACC(aq.y - bq.y, A, P) ACC(aq.y - bq.z, A, P) ACC(aq.y - bq.w, A, P) \
    ACC(aq.z - bq.x, A, P) ACC(aq.z - bq.y, A, P) ACC(aq.z - bq.z, A, P) ACC(aq.z - bq.w, A, P) \
    ACC(aq.w - bq.x, A, P) ACC(aq.w - bq.y, A, P) ACC(aq.w - bq.z, A, P) ACC(aq.w - bq.w, A, P)

__global__ __launch_bounds__(256, 8) void cpc_rows(const float* __restrict__ in,
                                                   const int* __restrict__ tgt,
                                                   double* __restrict__ acc) {
    __shared__ __align__(16) float sx[4][128];   // x*log2e; stride 512B (16B-aligned quads)

    const int tid = threadIdx.x;
    const int w   = tid >> 6;                    // wave = row-in-block
    const int l   = tid & 63;
    const int row = blockIdx.x * 4 + w;
    const float* x = in + row * NCLS;
    float* srow = sx[w];

    // ---- stage row (log2 domain) ----
    float x0 = x[l] * LOG2E;
    srow[l] = x0;
    float x1 = 0.f;
    const bool v1 = (l < NCLS - 64);             // lanes 0..35 hold a second class
    if (v1) { x1 = x[64 + l] * LOG2E; srow[64 + l] = x1; }
    __syncthreads();

    const int   t  = tgt[row];
    const float xt = srow[t];

    // ---- singles: sumexp, sum-x, and target-pair stats (shared exps) ----
    float At = 0.f, Pb = 1.f;
    float e2 = EXP2F(x0);
    float xs = x0;
    {
        float d = xt - x0;
        float a = fabsf(d);                      // l==t -> a=0 (At unaffected)
        float e = (l == t) ? 0.f : EXP2F(-a);
        At += a;  Pb = fmaf(Pb, e, Pb);
    }
    {
        int  k = 64 + l;
        float d = xt - x1;
        float a = v1 ? fabsf(d) : 0.f;
        float e = (v1 && k != t) ? EXP2F(-a) : 0.f;
        At += a;  Pb = fmaf(Pb, e, Pb);
        e2 += v1 ? EXP2F(x1) : 0.f;
        xs += v1 ? x1 : 0.f;
    }

    // ---- off-diagonal 4x4 tiles: 300 tiles, iters 0..3 full, iter 4 masked ----
    float Ao = 0.f, Po = 1.f;
#pragma unroll 1
    for (int it = 0; it < 4; ++it) {
        int idx = it * 64 + l;
        float s = sqrtf(fmaf(8.f, (float)idx, 1.f));
        int J = (int)((1.0f + s) * 0.5f);        // exact at column starts (odd-square sqrt)
        int I = idx - ((J * (J - 1)) >> 1);
        float4 aq = *(const float4*)(srow + 4 * I);
        float4 bq = *(const float4*)(srow + 4 * J);
        TILE16(aq, bq, Ao, Po)
    }
    {
        int idx = 256 + l;
        bool valid = idx < 300;
        int idxc = valid ? idx : 0;
        float s = sqrtf(fmaf(8.f, (float)idxc, 1.f));
        int J = (int)((1.0f + s) * 0.5f);
        int I = idxc - ((J * (J - 1)) >> 1);
        float4 aq = *(const float4*)(srow + 4 * I);
        float4 bq = *(const float4*)(srow + 4 * J);
        float As = Ao, Ps = Po;
        TILE16(aq, bq, Ao, Po)
        Ao = valid ? Ao : As;
        Po = valid ? Po : Ps;
    }

    // ---- diagonal tiles: lane<25 handles tile (l,l); all 16 entries, halved later ----
    float Ad = 0.f, Pd = 1.f;
    {
        bool valid = l < 25;
        int I = valid ? l : 0;
        float4 aq = *(const float4*)(srow + 4 * I);
        TILE16(aq, aq, Ad, Pd)
        Ad = valid ? Ad : 0.f;
        Pd = valid ? Pd : 1.f;
    }

    // ---- per-lane scalars, then wave reduce ----
    float lS  = Ao + 2.f * LOG2F(Po) + 0.5f * Ad + LOG2F(Pd);  // pair F-sums (+ self consts)
    float lPb = LOG2F(Pb);

    float r0 = e2, r1 = xs, r2 = At, r3 = lPb, r4 = lS;
#pragma unroll
    for (int off = 32; off; off >>= 1) {
        r0 += __shfl_xor(r0, off, 64);
        r1 += __shfl_xor(r1, off, 64);
        r2 += __shfl_xor(r2, off, 64);
        r3 += __shfl_xor(r3, off, 64);
        r4 += __shfl_xor(r4, off, 64);
    }

    if (l == 0) {
        float Fall = r4 - 100.f;                 // remove 25*4 self terms (f(0)=2, halved)
        float corr = r2 + 2.f * r3;              // F over target pairs
        double vce  = (double)(LN2 * (LOG2F(r0) - xt));                     // CE
        double vbdc = (double)(LN2 * (0.5f * (100.f * xt - r1 - r2) - r3)); // sum logsig(xt-rest)
        double vbec = (double)(LN2 * (corr - Fall - 99.f));                 // rest-pairs (+99*logsig(0))
        int slot = row & 31;
        unsafeAtomicAdd(acc +      slot, vce);
        unsafeAtomicAdd(acc + 32 + slot, vbdc);
        unsafeAtomicAdd(acc + 64 + slot, vbec);
    }
}

__global__ __launch_bounds__(192) void cpc_final(const double* __restrict__ acc,
                                                 float* __restrict__ out) {
    __shared__ double sred[3];
    const int tid = threadIdx.x;
    const int w = tid >> 6, l = tid & 63;
    double v = (l < 32) ? acc[w * 32 + l] : 0.0;   // w in {0,1,2}
#pragma unroll
    for (int off = 16; off; off >>= 1) v += __shfl_xor(v, off, 64);  // reduce lanes 0..31
    if (l == 0) sred[w] = v;
    __syncthreads();
    if (tid == 0) {
        double ce  = sred[0] / (double)NROWS;
        double bdc = -sred[1] / (double)(NCLS - 1) / (double)NROWS;
        double bec = -0.5 * sred[2] / (double)(NCLS - 1) / (double)(NCLS - 2) / (double)NROWS;
        out[0] = (float)(ce + bdc + bec);
        out[1] = (float)ce;
        out[2] = (float)bdc;
        out[3] = (float)bec;
    }
}

extern "C" void kernel_launch(void* const* d_in, const int* in_sizes, int n_in,
                              void* d_out, int out_size, void* d_ws, size_t ws_size,
                              hipStream_t stream) {
    const float* inputs  = (const float*)d_in[0];
    const int*   targets = (const int*)d_in[1];
    float*       out     = (float*)d_out;
    double*      acc     = (double*)d_ws;        // 3 comps x 32 slots = 768 B

    hipMemsetAsync(acc, 0, 96 * sizeof(double), stream);
    cpc_rows<<<NROWS / 4, 256, 0, stream>>>(inputs, targets, acc);
    cpc_final<<<1, 192, 0, stream>>>(acc, out);
}

// Round 8
// 23.011 us; speedup vs baseline: 2.9681x; 2.9681x over previous
//
#include <hip/hip_runtime.h>

#define NROWS 8192
#define NCLS  100
#define LN2   0.6931471805599453f
#define LOG2E 1.4426950408889634f

#if __has_builtin(__builtin_amdgcn_exp2f)
#define EXP2F(x) __builtin_amdgcn_exp2f(x)
#else
#define EXP2F(x) __expf((x) * LN2)
#endif
#if __has_builtin(__builtin_amdgcn_logf)
#define LOG2F(x) __builtin_amdgcn_logf(x)
#else
#define LOG2F(x) (__logf(x) * LOG2E)
#endif

// accumulate one symmetric pair-term: f(|d|) = |d| + 2*log2(1+2^-|d|)
// via A += |d|;  P *= (1 + 2^-|d|)   (abs/neg fold into VOP3 modifiers)
#define ACC(D0, A, P) { float d_ = (D0); A += fabsf(d_); \
                        P = fmaf(P, EXP2F(-fabsf(d_)), P); }

#define TILE16(aq, bq, A, P) \
    ACC(aq.x - bq.x, A, P) ACC(aq.x - bq.y, A, P) ACC(aq.x - bq.z, A, P) ACC(aq.x - bq.w, A, P) \
    ACC(aq.y - bq.x, A, P) ACC(aq.y - bq.y, A, P) ACC(aq.y - bq.z, A, P) ACC(aq.y - bq.w, A, P) \
    ACC(aq.z - bq.x, A, P) ACC(aq.z - bq.y, A, P) ACC(aq.z - bq.z, A, P) ACC(aq.z - bq.w, A, P) \
    ACC(aq.w - bq.x, A, P) ACC(aq.w - bq.y, A, P) ACC(aq.w - bq.z, A, P) ACC(aq.w - bq.w, A, P)

// idx in [0,300) -> strict-upper-triangle 4x4 tile coords (I < J), J in [1,25)
#define TILEIJ(idx, I, J) \
    float s_##I = sqrtf(fmaf(8.f, (float)(idx), 1.f)); \
    int J = (int)((1.0f + s_##I) * 0.5f); \
    int I = (idx) - ((J * (J - 1)) >> 1);

__global__ __launch_bounds__(256, 8) void cpc_rows(const float* __restrict__ in,
                                                   const int* __restrict__ tgt,
                                                   float* __restrict__ qb) {
    __shared__ __align__(16) float sx[4][128];   // x*log2e; 16B-aligned quads
    __shared__ float bred[4][3];

    const int tid = threadIdx.x;
    const int w   = tid >> 6;                    // wave = row-in-block
    const int l   = tid & 63;
    const int row = blockIdx.x * 4 + w;
    const float* x = in + row * NCLS;
    float* srow = sx[w];

    // ---- stage row (log2 domain) ----
    float x0 = x[l] * LOG2E;
    srow[l] = x0;
    float x1 = 0.f;
    const bool v1 = (l < NCLS - 64);             // lanes 0..35 hold a second class
    if (v1) { x1 = x[64 + l] * LOG2E; srow[64 + l] = x1; }
    __syncthreads();

    const int   t  = tgt[row];
    const float xt = srow[t];

    // ---- singles: sumexp, sum-x, and target-pair stats (shared exps) ----
    float At = 0.f, Pb = 1.f;
    float e2 = EXP2F(x0);
    float xs = x0;
    {
        float d = xt - x0;
        float a = fabsf(d);                      // l==t -> a=0 (At unaffected)
        float e = (l == t) ? 0.f : EXP2F(-a);
        At += a;  Pb = fmaf(Pb, e, Pb);
    }
    {
        int  k = 64 + l;
        float d = xt - x1;
        float a = v1 ? fabsf(d) : 0.f;
        float e = (v1 && k != t) ? EXP2F(-a) : 0.f;
        At += a;  Pb = fmaf(Pb, e, Pb);
        e2 += v1 ? EXP2F(x1) : 0.f;
        xs += v1 ? x1 : 0.f;
    }

    // ---- off-diagonal 4x4 tiles: 300 tiles; 2 tiles in flight per iter ----
    float AoA = 0.f, PoA = 1.f, AoB = 0.f, PoB = 1.f;
#pragma unroll 1
    for (int it = 0; it < 2; ++it) {
        int idxA = it * 128 + l;
        int idxB = idxA + 64;
        TILEIJ(idxA, IA, JA)
        TILEIJ(idxB, IB, JB)
        float4 aqA = *(const float4*)(srow + 4 * IA);
        float4 bqA = *(const float4*)(srow + 4 * JA);
        float4 aqB = *(const float4*)(srow + 4 * IB);
        float4 bqB = *(const float4*)(srow + 4 * JB);
        TILE16(aqA, bqA, AoA, PoA)
        TILE16(aqB, bqB, AoB, PoB)
    }
    {   // tail: idx = 256 + l, valid < 300
        int idx = 256 + l;
        bool valid = idx < 300;
        int idxc = valid ? idx : 0;
        TILEIJ(idxc, I, J)
        float4 aq = *(const float4*)(srow + 4 * I);
        float4 bq = *(const float4*)(srow + 4 * J);
        float As = AoA, Ps = PoA;
        TILE16(aq, bq, AoA, PoA)
        AoA = valid ? AoA : As;
        PoA = valid ? PoA : Ps;
    }

    // ---- diagonal tiles: lane<25 handles tile (l,l); all 16 entries, halved later ----
    float Ad = 0.f, Pd = 1.f;
    {
        bool valid = l < 25;
        int I = valid ? l : 0;
        float4 aq = *(const float4*)(srow + 4 * I);
        TILE16(aq, aq, Ad, Pd)
        Ad = valid ? Ad : 0.f;
        Pd = valid ? Pd : 1.f;
    }

    // ---- per-lane scalars, then wave reduce ----
    float lS  = (AoA + AoB) + 2.f * LOG2F(PoA * PoB) + 0.5f * Ad + LOG2F(Pd);
    float lPb = LOG2F(Pb);

    float r0 = e2, r1 = xs, r2 = At, r3 = lPb, r4 = lS;
#pragma unroll
    for (int off = 32; off; off >>= 1) {
        r0 += __shfl_xor(r0, off, 64);
        r1 += __shfl_xor(r1, off, 64);
        r2 += __shfl_xor(r2, off, 64);
        r3 += __shfl_xor(r3, off, 64);
        r4 += __shfl_xor(r4, off, 64);
    }

    if (l == 0) {
        float Fall = r4 - 100.f;                 // remove 25*4 self terms (f(0)=2, halved)
        float corr = r2 + 2.f * r3;              // F over target pairs
        bred[w][0] = LN2 * (LOG2F(r0) - xt);                     // CE
        bred[w][1] = LN2 * (0.5f * (100.f * xt - r1 - r2) - r3); // sum logsig(xt - rest)
        bred[w][2] = LN2 * (corr - Fall - 99.f);                 // rest-pairs (+99*logsig(0))
    }
    __syncthreads();
    if (tid < 3) {                               // 3 block-partials, SoA [3][nblocks]
        float s = bred[0][tid] + bred[1][tid] + bred[2][tid] + bred[3][tid];
        qb[tid * (NROWS / 4) + blockIdx.x] = s;
    }
}

__global__ __launch_bounds__(256) void cpc_final(const float* __restrict__ qb,
                                                 float* __restrict__ out) {
    __shared__ double sred[4][3];
    const int tid = threadIdx.x;
    const int lane = tid & 63, wid = tid >> 6;
    const int NB = NROWS / 4;                    // 2048 block-partials per component
    double a0 = 0, a1 = 0, a2 = 0;
#pragma unroll
    for (int it = 0; it < 2; ++it) {             // 2 x 256 x 4 = 2048
        int idx = (it * 256 + tid) * 4;
        float4 v0 = *(const float4*)(qb + idx);
        float4 v1 = *(const float4*)(qb + NB + idx);
        float4 v2 = *(const float4*)(qb + 2 * NB + idx);
        a0 += (double)v0.x; a0 += (double)v0.y; a0 += (double)v0.z; a0 += (double)v0.w;
        a1 += (double)v1.x; a1 += (double)v1.y; a1 += (double)v1.z; a1 += (double)v1.w;
        a2 += (double)v2.x; a2 += (double)v2.y; a2 += (double)v2.z; a2 += (double)v2.w;
    }
#pragma unroll
    for (int off = 32; off; off >>= 1) {
        a0 += __shfl_xor(a0, off, 64);
        a1 += __shfl_xor(a1, off, 64);
        a2 += __shfl_xor(a2, off, 64);
    }
    if (lane == 0) { sred[wid][0] = a0; sred[wid][1] = a1; sred[wid][2] = a2; }
    __syncthreads();
    if (tid == 0) {
        double ce  = (sred[0][0] + sred[1][0] + sred[2][0] + sred[3][0]) / (double)NROWS;
        double bdc = -(sred[0][1] + sred[1][1] + sred[2][1] + sred[3][1])
                     / (double)(NCLS - 1) / (double)NROWS;
        double bec = -0.5 * (sred[0][2] + sred[1][2] + sred[2][2] + sred[3][2])
                     / (double)(NCLS - 1) / (double)(NCLS - 2) / (double)NROWS;
        out[0] = (float)(ce + bdc + bec);
        out[1] = (float)ce;
        out[2] = (float)bdc;
        out[3] = (float)bec;
    }
}

extern "C" void kernel_launch(void* const* d_in, const int* in_sizes, int n_in,
                              void* d_out, int out_size, void* d_ws, size_t ws_size,
                              hipStream_t stream) {
    const float* inputs  = (const float*)d_in[0];
    const int*   targets = (const int*)d_in[1];
    float*       out     = (float*)d_out;
    float*       qb      = (float*)d_ws;         // [3][2048] f32 block partials = 24 KB

    cpc_rows<<<NROWS / 4, 256, 0, stream>>>(inputs, targets, qb);
    cpc_final<<<1, 256, 0, stream>>>(qb, out);
}

// Round 9
// 15.022 us; speedup vs baseline: 4.5465x; 1.5318x over previous
//
#include <hip/hip_runtime.h>

#define NROWS 8192
#define NCLS  100
#define LN2   0.6931471805599453f
#define LOG2E 1.4426950408889634f

#if __has_builtin(__builtin_amdgcn_exp2f)
#define EXP2F(x) __builtin_amdgcn_exp2f(x)
#else
#define EXP2F(x) __expf((x) * LN2)
#endif
#if __has_builtin(__builtin_amdgcn_logf)
#define LOG2F(x) __builtin_amdgcn_logf(x)
#else
#define LOG2F(x) (__logf(x) * LOG2E)
#endif

// one pair term, h-form: P *= (Ei*Rj + Ej*Ri) = 2^-4 * (2^(d/2) + 2^(-d/2))
// where E = 2^((x-4)/2), R = 2^(-(x+4)/2).  f(|d|) = 2*log2(h) + 8.  3 VALU, 0 trans.
#define HT(EA, RA, EB, RB, P) { P *= fmaf((EB), (RA), (EA) * (RB)); }

#define TILE16H(Ea, Ra, Eb, Rb, P0, P1, P2, P3) \
  HT(Ea.x, Ra.x, Eb.x, Rb.x, P0) HT(Ea.x, Ra.x, Eb.y, Rb.y, P0) \
  HT(Ea.x, Ra.x, Eb.z, Rb.z, P0) HT(Ea.x, Ra.x, Eb.w, Rb.w, P0) \
  HT(Ea.y, Ra.y, Eb.x, Rb.x, P1) HT(Ea.y, Ra.y, Eb.y, Rb.y, P1) \
  HT(Ea.y, Ra.y, Eb.z, Rb.z, P1) HT(Ea.y, Ra.y, Eb.w, Rb.w, P1) \
  HT(Ea.z, Ra.z, Eb.x, Rb.x, P2) HT(Ea.z, Ra.z, Eb.y, Rb.y, P2) \
  HT(Ea.z, Ra.z, Eb.z, Rb.z, P2) HT(Ea.z, Ra.z, Eb.w, Rb.w, P2) \
  HT(Ea.w, Ra.w, Eb.x, Rb.x, P3) HT(Ea.w, Ra.w, Eb.y, Rb.y, P3) \
  HT(Ea.w, Ra.w, Eb.z, Rb.z, P3) HT(Ea.w, Ra.w, Eb.w, Rb.w, P3)

// idx in [0,300) -> strict-upper-triangle 4x4 tile coords (I < J), J in [1,25)
#define TILEIJ(idx, I, J) \
    float s_##I = sqrtf(fmaf(8.f, (float)(idx), 1.f)); \
    int J = (int)((1.0f + s_##I) * 0.5f); \
    int I = (idx) - ((J * (J - 1)) >> 1);

__global__ __launch_bounds__(256, 8) void cpc_rows(const float* __restrict__ in,
                                                   const int* __restrict__ tgt,
                                                   float* __restrict__ qb) {
    __shared__ __align__(16) float sx[4][128], sE[4][128], sR[4][128];
    __shared__ float bred[4][3];

    const int tid = threadIdx.x;
    const int w   = tid >> 6;                    // wave = row-in-block
    const int l   = tid & 63;
    const int row = blockIdx.x * 4 + w;
    const float* x = in + row * NCLS;

    // ---- stage (x', E, R) in log2 domain ----
    float x0 = x[l] * LOG2E;
    float E0 = EXP2F((x0 - 4.f) * 0.5f);
    float R0 = EXP2F((x0 + 4.f) * -0.5f);
    sx[w][l] = x0; sE[w][l] = E0; sR[w][l] = R0;
    const bool v1 = (l < NCLS - 64);             // lanes 0..35 hold a second class
    float x1 = 0.f, E1 = 0.f;
    if (v1) {
        x1 = x[64 + l] * LOG2E;
        E1 = EXP2F((x1 - 4.f) * 0.5f);
        float R1 = EXP2F((x1 + 4.f) * -0.5f);
        sx[w][64 + l] = x1; sE[w][64 + l] = E1; sR[w][64 + l] = R1;
    }
    __syncthreads();

    const int   t  = tgt[row];
    const float xt = sx[w][t];

    // ---- singles: sumexp (via E^2), sum-x, target-pair stats ----
    float At, Pb, es, xs;
    {
        float a0 = fabsf(xt - x0);
        float e0 = (l == t) ? 0.f : EXP2F(-a0);
        At = a0; Pb = 1.f + e0;
        es = E0 * E0;                            // = 2^(x0-4)
        xs = x0;
    }
    {
        float a1 = v1 ? fabsf(xt - x1) : 0.f;
        float e1 = (v1 && (64 + l) != t) ? EXP2F(-fabsf(xt - x1)) : 0.f;
        At += a1; Pb = fmaf(Pb, e1, Pb);
        es = v1 ? fmaf(E1, E1, es) : es;
        xs += x1;                                // x1 = 0 when !v1
    }
    float lPb = LOG2F(Pb);

    const float* pE = sE[w];
    const float* pR = sR[w];

    // ---- off-diagonal 4x4 tiles: 300 tiles; products of h, no trans in loop ----
    float P0 = 1.f, P1 = 1.f, P2 = 1.f, P3 = 1.f;
    float cst = 512.f;                           // 4 iters x 16 terms x 8
#pragma unroll 1
    for (int it = 0; it < 4; ++it) {
        int idx = it * 64 + l;
        TILEIJ(idx, I, J)
        float4 Ea = *(const float4*)(pE + 4 * I);
        float4 Ra = *(const float4*)(pR + 4 * I);
        float4 Eb = *(const float4*)(pE + 4 * J);
        float4 Rb = *(const float4*)(pR + 4 * J);
        TILE16H(Ea, Ra, Eb, Rb, P0, P1, P2, P3)
    }
    {   // tail: idx = 256 + l, valid < 300
        int idx = 256 + l;
        bool tv = idx < 300;
        int idxc = tv ? idx : 0;
        TILEIJ(idxc, I, J)
        float4 Ea = *(const float4*)(pE + 4 * I);
        float4 Ra = *(const float4*)(pR + 4 * I);
        float4 Eb = *(const float4*)(pE + 4 * J);
        float4 Rb = *(const float4*)(pR + 4 * J);
        float S0 = P0, S1 = P1, S2 = P2, S3 = P3;
        TILE16H(Ea, Ra, Eb, Rb, P0, P1, P2, P3)
        P0 = tv ? P0 : S0; P1 = tv ? P1 : S1;
        P2 = tv ? P2 : S2; P3 = tv ? P3 : S3;
        cst += tv ? 128.f : 0.f;
    }
    // ---- diagonal tiles: lane<25 -> tile (l,l); all 16 entries; pairs doubled, 4 selfs ----
    float Pd0 = 1.f, Pd1 = 1.f;
    {
        bool dv = l < 25;
        int I = dv ? l : 0;
        float4 Ea = *(const float4*)(pE + 4 * I);
        float4 Ra = *(const float4*)(pR + 4 * I);
        TILE16H(Ea, Ra, Ea, Ra, Pd0, Pd1, Pd0, Pd1)
        Pd0 = dv ? Pd0 : 1.f;
        Pd1 = dv ? Pd1 : 1.f;
        cst += dv ? 64.f : 0.f;                  // 6 pairs*8 + 12 self-scale + 4 self-val
    }

    // lS = sum of f over assigned pairs (+ halved selfs), log2 units
    float lS = 2.f * ((LOG2F(P0) + LOG2F(P1)) + (LOG2F(P2) + LOG2F(P3)))
             + LOG2F(Pd0 * Pd1) + cst;

    // ---- packed reduce: 3 values ----
    float r0 = es;                               // -> sumexp * 2^-4
    float rU = xs + At + 2.f * lPb;              // -> q1
    float rW = At + 2.f * lPb - lS;              // -> q2
#pragma unroll
    for (int off = 32; off; off >>= 1) {
        r0 += __shfl_xor(r0, off, 64);
        rU += __shfl_xor(rU, off, 64);
        rW += __shfl_xor(rW, off, 64);
    }
    if (l == 0) {
        bred[w][0] = LN2 * (LOG2F(r0) + 4.f - xt);        // CE
        bred[w][1] = LN2 * (50.f * xt - 0.5f * rU);       // sum logsig(xt - rest)
        bred[w][2] = LN2 * (rW + 1.f);                    // rest-pairs (+99*logsig(0))
    }
    __syncthreads();
    if (tid < 3) {                               // 3 block-partials, SoA [3][nblocks]
        float s = bred[0][tid] + bred[1][tid] + bred[2][tid] + bred[3][tid];
        qb[tid * (NROWS / 4) + blockIdx.x] = s;
    }
}

__global__ __launch_bounds__(256) void cpc_final(const float* __restrict__ qb,
                                                 float* __restrict__ out) {
    __shared__ double sred[4][3];
    const int tid = threadIdx.x;
    const int lane = tid & 63, wid = tid >> 6;
    const int NB = NROWS / 4;                    // 2048 block-partials per component
    double a0 = 0, a1 = 0, a2 = 0;
#pragma unroll
    for (int it = 0; it < 2; ++it) {             // 2 x 256 x 4 = 2048
        int idx = (it * 256 + tid) * 4;
        float4 v0 = *(const float4*)(qb + idx);
        float4 v1 = *(const float4*)(qb + NB + idx);
        float4 v2 = *(const float4*)(qb + 2 * NB + idx);
        a0 += (double)v0.x; a0 += (double)v0.y; a0 += (double)v0.z; a0 += (double)v0.w;
        a1 += (double)v1.x; a1 += (double)v1.y; a1 += (double)v1.z; a1 += (double)v1.w;
        a2 += (double)v2.x; a2 += (double)v2.y; a2 += (double)v2.z; a2 += (double)v2.w;
    }
#pragma unroll
    for (int off = 32; off; off >>= 1) {
        a0 += __shfl_xor(a0, off, 64);
        a1 += __shfl_xor(a1, off, 64);
        a2 += __shfl_xor(a2, off, 64);
    }
    if (lane == 0) { sred[wid][0] = a0; sred[wid][1] = a1; sred[wid][2] = a2; }
    __syncthreads();
    if (tid == 0) {
        double ce  = (sred[0][0] + sred[1][0] + sred[2][0] + sred[3][0]) / (double)NROWS;
        double bdc = -(sred[0][1] + sred[1][1] + sred[2][1] + sred[3][1])
                     / (double)(NCLS - 1) / (double)NROWS;
        double bec = -0.5 * (sred[0][2] + sred[1][2] + sred[2][2] + sred[3][2])
                     / (double)(NCLS - 1) / (double)(NCLS - 2) / (double)NROWS;
        out[0] = (float)(ce + bdc + bec);
        out[1] = (float)ce;
        out[2] = (float)bdc;
        out[3] = (float)bec;
    }
}

extern "C" void kernel_launch(void* const* d_in, const int* in_sizes, int n_in,
                              void* d_out, int out_size, void* d_ws, size_t ws_size,
                              hipStream_t stream) {
    const float* inputs  = (const float*)d_in[0];
    const int*   targets = (const int*)d_in[1];
    float*       out     = (float*)d_out;
    float*       qb      = (float*)d_ws;         // [3][2048] f32 block partials = 24 KB

    cpc_rows<<<NROWS / 4, 256, 0, stream>>>(inputs, targets, qb);
    cpc_final<<<1, 256, 0, stream>>>(qb, out);
}